// Round 1
// baseline (204.843 us; speedup 1.0000x reference)
//
#include <hip/hip_runtime.h>
#include <math.h>

// DistMult: out[b] = sigmoid( sum_d head[b,d] * rel[rel_ids[b], d] * tail[b,d] )
// B = 262144, D = 512, R = 1000. Pure memory-bound streaming reduction.
//
// Layout: one 64-lane wave per row b. Each lane handles 8 elements (2 x float4),
// so a wave's loads cover the full 2KB row contiguously (coalesced 1KB/instr).
// rel_embeds is 2MB -> L2-resident, gather is cheap.

__global__ __launch_bounds__(256) void distmult_kernel(
    const float* __restrict__ head,
    const float* __restrict__ tail,
    const int*   __restrict__ rel_ids,
    const float* __restrict__ rel,
    float* __restrict__ out,
    int B)
{
    const int lane  = threadIdx.x & 63;
    const int wid   = threadIdx.x >> 6;           // wave index in block
    const int wpb   = blockDim.x >> 6;            // waves per block (4)
    const int wstride = gridDim.x * wpb;          // total waves in grid

    for (int row = blockIdx.x * wpb + wid; row < B; row += wstride) {
        const int r = rel_ids[row];

        const float4* __restrict__ h4 = reinterpret_cast<const float4*>(head + (size_t)row * 512);
        const float4* __restrict__ t4 = reinterpret_cast<const float4*>(tail + (size_t)row * 512);
        const float4* __restrict__ r4 = reinterpret_cast<const float4*>(rel  + (size_t)r   * 512);

        float acc = 0.0f;
        #pragma unroll
        for (int i = 0; i < 2; ++i) {
            const int idx = lane + i * 64;        // float4 index within row (0..127)
            const float4 h = h4[idx];
            const float4 t = t4[idx];
            const float4 v = r4[idx];
            acc += h.x * v.x * t.x;
            acc += h.y * v.y * t.y;
            acc += h.z * v.z * t.z;
            acc += h.w * v.w * t.w;
        }

        // 64-lane butterfly reduction
        #pragma unroll
        for (int off = 32; off > 0; off >>= 1)
            acc += __shfl_xor(acc, off, 64);

        if (lane == 0)
            out[row] = 1.0f / (1.0f + __expf(-acc));
    }
}

extern "C" void kernel_launch(void* const* d_in, const int* in_sizes, int n_in,
                              void* d_out, int out_size, void* d_ws, size_t ws_size,
                              hipStream_t stream) {
    const float* head    = (const float*)d_in[0];
    const float* tail    = (const float*)d_in[1];
    const int*   rel_ids = (const int*)  d_in[2];
    const float* rel     = (const float*)d_in[3];
    float*       out     = (float*)d_out;

    const int B = in_sizes[2];        // number of triples (rel_ids count)

    const int block = 256;            // 4 waves/block
    const int wpb   = block / 64;
    int grid = (B + wpb - 1) / wpb;   // one wave per row if launched fully
    if (grid > 4096) grid = 4096;     // grid-stride: keep scheduler room, amortize launch

    distmult_kernel<<<grid, block, 0, stream>>>(head, tail, rel_ids, rel, out, B);
}

// Round 3
// 163.405 us; speedup vs baseline: 1.2536x; 1.2536x over previous
//
#include <hip/hip_runtime.h>
#include <math.h>

// DistMult: out[b] = sigmoid( sum_d head[b,d] * rel[rel_ids[b], d] * tail[b,d] )
// B = 262144, D = 512, R = 1000. Memory-bound streaming reduction.
//
// One 64-lane wave handles TWO rows per iteration (12 outstanding 16B loads,
// two interleaved reduction chains). head/tail are streamed with the
// non-temporal hint (read exactly once); rel (2 MB) stays L2-resident.
//
// NOTE: __builtin_nontemporal_load requires a NATIVE vector type, not HIP's
// float4 class -> use ext_vector_type(4).

typedef float f32x4 __attribute__((ext_vector_type(4)));

__device__ __forceinline__ float sigmoidf(float x) {
    return 1.0f / (1.0f + __expf(-x));
}

__global__ __launch_bounds__(256) void distmult_kernel(
    const float* __restrict__ head,
    const float* __restrict__ tail,
    const int*   __restrict__ rel_ids,
    const float* __restrict__ rel,
    float* __restrict__ out,
    int B)
{
    const int lane   = threadIdx.x & 63;
    const int wid    = threadIdx.x >> 6;          // wave index in block
    const int wpb    = blockDim.x >> 6;           // waves per block (4)
    const int gwave  = blockIdx.x * wpb + wid;
    const int nwaves = gridDim.x * wpb;

    for (int row = gwave * 2; row < B; row += nwaves * 2) {
        const bool has2 = (row + 1 < B);
        const int  row1 = has2 ? (row + 1) : row;

        const int r0 = rel_ids[row];
        const int r1 = rel_ids[row1];

        const f32x4* __restrict__ h0 = reinterpret_cast<const f32x4*>(head + (size_t)row  * 512);
        const f32x4* __restrict__ h1 = reinterpret_cast<const f32x4*>(head + (size_t)row1 * 512);
        const f32x4* __restrict__ t0 = reinterpret_cast<const f32x4*>(tail + (size_t)row  * 512);
        const f32x4* __restrict__ t1 = reinterpret_cast<const f32x4*>(tail + (size_t)row1 * 512);
        const f32x4* __restrict__ v0 = reinterpret_cast<const f32x4*>(rel  + (size_t)r0   * 512);
        const f32x4* __restrict__ v1 = reinterpret_cast<const f32x4*>(rel  + (size_t)r1   * 512);

        // Issue all loads up front: 12 x 16B per lane in flight.
        const f32x4 ha0 = __builtin_nontemporal_load(h0 + lane);
        const f32x4 ha1 = __builtin_nontemporal_load(h0 + lane + 64);
        const f32x4 hb0 = __builtin_nontemporal_load(h1 + lane);
        const f32x4 hb1 = __builtin_nontemporal_load(h1 + lane + 64);
        const f32x4 ta0 = __builtin_nontemporal_load(t0 + lane);
        const f32x4 ta1 = __builtin_nontemporal_load(t0 + lane + 64);
        const f32x4 tb0 = __builtin_nontemporal_load(t1 + lane);
        const f32x4 tb1 = __builtin_nontemporal_load(t1 + lane + 64);
        const f32x4 va0 = v0[lane];
        const f32x4 va1 = v0[lane + 64];
        const f32x4 vb0 = v1[lane];
        const f32x4 vb1 = v1[lane + 64];

        float acc0 = 0.0f, acc1 = 0.0f;
        acc0 += ha0.x * va0.x * ta0.x;  acc0 += ha0.y * va0.y * ta0.y;
        acc0 += ha0.z * va0.z * ta0.z;  acc0 += ha0.w * va0.w * ta0.w;
        acc0 += ha1.x * va1.x * ta1.x;  acc0 += ha1.y * va1.y * ta1.y;
        acc0 += ha1.z * va1.z * ta1.z;  acc0 += ha1.w * va1.w * ta1.w;

        acc1 += hb0.x * vb0.x * tb0.x;  acc1 += hb0.y * vb0.y * tb0.y;
        acc1 += hb0.z * vb0.z * tb0.z;  acc1 += hb0.w * vb0.w * tb0.w;
        acc1 += hb1.x * vb1.x * tb1.x;  acc1 += hb1.y * vb1.y * tb1.y;
        acc1 += hb1.z * vb1.z * tb1.z;  acc1 += hb1.w * vb1.w * tb1.w;

        // Two interleaved 64-lane butterfly reductions (independent chains).
        #pragma unroll
        for (int off = 32; off > 0; off >>= 1) {
            acc0 += __shfl_xor(acc0, off, 64);
            acc1 += __shfl_xor(acc1, off, 64);
        }

        if (lane == 0) {
            if (has2) {
                float2 o;
                o.x = sigmoidf(acc0);
                o.y = sigmoidf(acc1);
                *reinterpret_cast<float2*>(out + row) = o;   // row is even
            } else {
                out[row] = sigmoidf(acc0);
            }
        }
    }
}

extern "C" void kernel_launch(void* const* d_in, const int* in_sizes, int n_in,
                              void* d_out, int out_size, void* d_ws, size_t ws_size,
                              hipStream_t stream) {
    const float* head    = (const float*)d_in[0];
    const float* tail    = (const float*)d_in[1];
    const int*   rel_ids = (const int*)  d_in[2];
    const float* rel     = (const float*)d_in[3];
    float*       out     = (float*)d_out;

    const int B = in_sizes[2];        // number of triples (rel_ids count)

    const int block = 256;            // 4 waves/block
    const int wpb   = block / 64;
    const int rows_per_block = 2 * wpb;                 // 2 rows per wave-iter
    int grid = (B + rows_per_block - 1) / rows_per_block;
    if (grid > 8192) grid = 8192;     // grid-stride the rest

    distmult_kernel<<<grid, block, 0, stream>>>(head, tail, rel_ids, rel, out, B);
}